// Round 11
// baseline (2210.550 us; speedup 1.0000x reference)
//
#include <hip/hip_runtime.h>

// Problem constants
#define NMAT 50
#define BATCH 128
#define FDIM 1024
#define HDIM 4096
#define ROWS 6400            // BATCH*NMAT
#define PSIZE 320000         // BATCH*NMAT*NMAT
#define HINF 1e18

// ws layout (bytes):
//   M64 : [0, 2560000)        fp64 [6400][50]; psi64 in-place after sinkhorn
//   hbuf: [2560000, ...)      fp64 [max_rows][4096]
#define WS_M_OFF   0
#define WS_H_OFF   2560000LL
#define WS_MIN     (WS_H_OFF + 128LL * HDIM * 8)   // ~6.75 MB

// ---------------- GEMM1 (fp64): h = leaky(x @ W1 + b1) ----------------------
// 64x64 tile, 256 threads, 4x4 fp64 acc per thread. (Numerics identical to the
// round-7 proof-carrying version: per-output k-sequential fma chain.)
__global__ __launch_bounds__(256) void gemm1_f64(
    const float* __restrict__ X,     // chunk base [rows][1024] fp32
    const float* __restrict__ W1,    // [1024][4096] fp32
    const float* __restrict__ b1,    // [4096] fp32
    double* __restrict__ Hout) {     // chunk base [rows][4096] fp64
  __shared__ __align__(16) double As[32][68];   // [k][m], padded
  __shared__ __align__(16) double Bs[32][68];   // [k][n], padded
  int t = threadIdx.x;
  int nt = blockIdx.x & 63;      // 4096/64 n-tiles; inner for x L2 reuse
  int mt = blockIdx.x >> 6;
  int m0 = mt * 64, n0 = nt * 64;
  int tm = t & 15, tn = t >> 4;

  double acc[4][4];
#pragma unroll
  for (int r = 0; r < 4; ++r)
#pragma unroll
    for (int c = 0; c < 4; ++c) acc[r][c] = 0.0;

  for (int k0 = 0; k0 < FDIM; k0 += 32) {
    __syncthreads();
#pragma unroll
    for (int e = 0; e < 8; ++e) {
      int i = t * 8 + e;               // 0..2047, each exactly once
      int ka = i & 31, ma = i >> 5;    // A: 64 m x 32 k
      As[ka][ma] = (double)X[(size_t)(m0 + ma) * FDIM + k0 + ka];
      int nb = i & 63, kb = i >> 6;    // B: 32 k x 64 n
      Bs[kb][nb] = (double)W1[(size_t)(k0 + kb) * HDIM + n0 + nb];
    }
    __syncthreads();
#pragma unroll 4
    for (int kk = 0; kk < 32; ++kk) {
      double a[4], b[4];
      *(double2*)&a[0] = *(const double2*)&As[kk][tm * 4];
      *(double2*)&a[2] = *(const double2*)&As[kk][tm * 4 + 2];
      *(double2*)&b[0] = *(const double2*)&Bs[kk][tn * 4];
      *(double2*)&b[2] = *(const double2*)&Bs[kk][tn * 4 + 2];
#pragma unroll
      for (int r = 0; r < 4; ++r)
#pragma unroll
        for (int c = 0; c < 4; ++c) acc[r][c] = fma(a[r], b[c], acc[r][c]);
    }
  }

  int gm = m0 + tm * 4, gn = n0 + tn * 4;
#pragma unroll
  for (int c = 0; c < 4; ++c) {
    double bias = (double)b1[gn + c];
#pragma unroll
    for (int r = 0; r < 4; ++r) {
      double v = acc[r][c] + bias;
      v = v >= 0.0 ? v : 0.01 * v;     // leaky_relu fp64
      Hout[(size_t)(gm + r) * HDIM + gn + c] = v;
    }
  }
}

// ---------------- GEMM2: M = h @ W2 (fp64, full K per block) ----------------
__global__ __launch_bounds__(256) void gemm2_kernel(
    const double* __restrict__ hchunk,       // chunk base [rows][4096] fp64
    const float* __restrict__ W2,            // [4096][50] fp32
    double* __restrict__ M64,                // [6400][50]
    int row0) {
  __shared__ __align__(16) double hs[32 * 64];
  __shared__ float w2s[64 * 52];
  int t = threadIdx.x;
  int c = t & 63, g = t >> 6;                // g = wave id; rows g, g+4, ..., g+28
  double acc[8] = {0, 0, 0, 0, 0, 0, 0, 0};
  const double* hbase = hchunk + (size_t)blockIdx.x * 32 * HDIM;

  for (int k0 = 0; k0 < HDIM; k0 += 64) {
    __syncthreads();
    {
      int row = t >> 3, seg = (t & 7) * 8;
      const double2* src = (const double2*)(hbase + (size_t)row * HDIM + k0 + seg);
      double2 v0 = src[0], v1 = src[1], v2 = src[2], v3 = src[3];
      double2* dst = (double2*)(hs + row * 64 + seg);
      dst[0] = v0; dst[1] = v1; dst[2] = v2; dst[3] = v3;
    }
    for (int idx = t; idx < 3200; idx += 256) {     // 64 k x 50 c, coalesced
      int cc = idx % 50, kk = idx / 50;
      w2s[kk * 52 + cc] = W2[(size_t)k0 * NMAT + idx];
    }
    __syncthreads();
    if (c < NMAT) {
#pragma unroll 4
      for (int kk = 0; kk < 64; kk += 2) {
        double w0 = (double)w2s[kk * 52 + c];
        double w1 = (double)w2s[kk * 52 + 52 + c];
#pragma unroll
        for (int i = 0; i < 8; ++i) {
          double2 hv = *(const double2*)&hs[(g + i * 4) * 64 + kk];   // broadcast
          acc[i] = fma(hv.x, w0, acc[i]);
          acc[i] = fma(hv.y, w1, acc[i]);
        }
      }
    }
  }
  if (c < NMAT) {
#pragma unroll
    for (int i = 0; i < 8; ++i)
      M64[(size_t)(row0 + blockIdx.x * 32 + g + i * 4) * NMAT + c] = acc[i];
  }
}

// ---------------- Sinkhorn (fp64): P=exp(leaky(M+b2)); 5x row/col norm ------
// Reads M64, writes psi64 IN-PLACE over M64; psi/X outputs are FP32.
__global__ __launch_bounds__(64) void sinkhorn_kernel(
    double* __restrict__ M64, const float* __restrict__ b2,
    float* __restrict__ out_psi, float* __restrict__ out_X) {
  int b = blockIdx.x, lane = threadIdx.x;
  __shared__ double P[2500];
  __shared__ double rs[50];
  const size_t base = (size_t)b * 2500;
  for (int e = lane; e < 2500; e += 64) {
    double m = M64[base + e] + (double)b2[e % 50];
    m = m >= 0.0 ? m : 0.01 * m;      // leaky_relu in fp64
    P[e] = exp(m);                    // TAU = 1.0
  }
  __syncthreads();
  for (int it = 0; it < 5; ++it) {
    if (lane < 50) { double s = 0; for (int j = 0; j < 50; ++j) s += P[lane * 50 + j]; rs[lane] = s; }
    __syncthreads();
    for (int e = lane; e < 2500; e += 64) P[e] /= rs[e / 50];   // axis=2
    __syncthreads();
    if (lane < 50) { double s = 0; for (int r = 0; r < 50; ++r) s += P[r * 50 + lane]; rs[lane] = s; }
    __syncthreads();
    for (int e = lane; e < 2500; e += 64) P[e] /= rs[e % 50];   // axis=1
    __syncthreads();
  }
  for (int e = lane; e < 2500; e += 64) {
    double pv = P[e];
    M64[base + e] = pv;               // psi64 in-place
    float f = (float)pv;
    out_psi[base + e] = f;
    out_X[base + e] = f;              // ALPHA=1.0 => X == psi exactly
  }
}

// ---------------- Hungarian (exact replica of the reference's algorithm, ----
// including its dead-minv behavior), fp64, one wave per batch. FP32 outputs.
__global__ __launch_bounds__(64) void hungarian_kernel(
    const double* __restrict__ psi64, float* __restrict__ out_perms,
    float* __restrict__ out_dist) {
  int b = blockIdx.x, lane = threadIdx.x;
  __shared__ double cost[2500];
  __shared__ double u[51];
  __shared__ int p[51];
  __shared__ int wayl[51];
  const double* P = psi64 + (size_t)b * 2500;
  for (int e = lane; e < 2500; e += 64) cost[e] = -P[e];
  if (lane < 51) { u[lane] = 0.0; p[lane] = 0; }
  __syncthreads();
  double v = 0.0;                      // v[lane+1]
  bool lactive = lane < NMAT;

  for (int i = 1; i <= NMAT; ++i) {
    bool used = false;
    int way = 0;
    int j0 = 0, j1 = 0;
    for (int guard = 0; guard < 64; ++guard) {   // defensive cap (normally <=51)
      if (lane == j0 - 1) used = true;           // used[j0] = True (j0>=1)
      int i0 = (j0 == 0) ? i : p[j0];
      double ui0 = u[i0];
      double cand = HINF;
      if (lactive && !used) {
        cand = cost[(i0 - 1) * NMAT + lane] - ui0 - v;
        way = j0;                                // way set for ALL free cols (dead-minv)
      }
      double m = cand;
#pragma unroll
      for (int s = 32; s > 0; s >>= 1) {
        double o = __shfl_xor(m, s, 64);
        m = (o < m) ? o : m;
      }
      unsigned long long bal = __ballot(cand == m);
      j1 = (int)__builtin_ctzll(bal) + 1;        // np.argmin tie-break: lowest j
      double delta = m;
      __syncthreads();
      if (used) { v -= delta; u[p[lane + 1]] += delta; }   // distinct rows, no race
      if (lane == 63) u[i] += delta;                       // j=0 column: p[0]=i
      __syncthreads();
      j0 = j1;
      if (p[j0] == 0) break;
    }
    if (lactive) wayl[lane + 1] = way;
    __syncthreads();
    if (lane == 0) {                   // augment (serial, path <= 50)
      int j = j1;
      while (j != 0) {
        int jw = wayl[j];
        p[j] = (jw == 0) ? i : p[jw];
        j = jw;
      }
    }
    __syncthreads();
  }

  // perms one-hot + dist (fp32 outputs)
  size_t pbase = (size_t)b * 2500;
  for (int e = lane; e < 2500; e += 64) out_perms[pbase + e] = 0.0f;
  __syncthreads();
  double val = 0.0;
  if (lactive) {
    int row = p[lane + 1] - 1;
    if (row < 0) row = 0;              // defensive clamp (provably unreachable)
    if (row > 49) row = 49;
    out_perms[pbase + (size_t)row * NMAT + lane] = 1.0f;
    val = P[(size_t)row * NMAT + lane];
  }
#pragma unroll
  for (int s = 32; s > 0; s >>= 1) val += __shfl_xor(val, s, 64);
  if (lane == 0) out_dist[b] = (float)(val / (double)NMAT);
}

// ---------------------------------------------------------------------------
extern "C" void kernel_launch(void* const* d_in, const int* in_sizes, int n_in,
                              void* d_out, int out_size, void* d_ws, size_t ws_size,
                              hipStream_t stream) {
  const float* x  = (const float*)d_in[0];   // fp32 per the reference dtypes
  const float* W1 = (const float*)d_in[1];
  const float* b1 = (const float*)d_in[2];
  const float* W2 = (const float*)d_in[3];
  const float* b2 = (const float*)d_in[4];
  float* out = (float*)d_out;                // OUTPUTS ARE FLOAT32 (round-8 finding)
  float* out_psi   = out;
  float* out_perms = out + PSIZE;
  float* out_X     = out + 2 * PSIZE;
  float* out_dist  = out + 3 * PSIZE;

  if (ws_size < (size_t)WS_MIN) return;   // diagnostic: outputs stay 0

  char* ws = (char*)d_ws;
  double* M64 = (double*)(ws + WS_M_OFF);
  double* hbuf = (double*)(ws + WS_H_OFF);
  long long avail = (long long)ws_size - WS_H_OFF;
  int max_rows = (int)(avail / (HDIM * 8));
  max_rows = (max_rows / 128) * 128;
  if (max_rows > ROWS) max_rows = ROWS;

  for (int r0 = 0; r0 < ROWS; r0 += max_rows) {
    int rows = (ROWS - r0 < max_rows) ? (ROWS - r0) : max_rows;
    hipLaunchKernelGGL(gemm1_f64, dim3((rows / 64) * 64), dim3(256), 0, stream,
                       x + (size_t)r0 * FDIM, W1, b1, hbuf);
    hipLaunchKernelGGL(gemm2_kernel, dim3(rows / 32), dim3(256), 0, stream,
                       hbuf, W2, M64, r0);
  }
  hipLaunchKernelGGL(sinkhorn_kernel, dim3(BATCH), dim3(64), 0, stream,
                     M64, b2, out_psi, out_X);
  hipLaunchKernelGGL(hungarian_kernel, dim3(BATCH), dim3(64), 0, stream,
                     M64, out_perms, out_dist);
}

// Round 13
// 1406.951 us; speedup vs baseline: 1.5712x; 1.5712x over previous
//
#include <hip/hip_runtime.h>

// Problem constants
#define NMAT 50
#define BATCH 128
#define FDIM 1024
#define HDIM 4096
#define ROWS 6400            // BATCH*NMAT
#define PSIZE 320000         // BATCH*NMAT*NMAT
#define HINF 1e18

// ws layout (bytes):
//   M64 : [0, 2560000)        fp64 [6400][50]; psi64 in-place after sinkhorn
//   hbuf: [2560000, ...)      fp32 [max_rows][4096]
#define WS_M_OFF   0
#define WS_H_OFF   2560000LL
#define WS_MIN     (WS_H_OFF + 128LL * HDIM * 4)   // ~4.66 MB

// ---------------- GEMM1 (fp32): h = leaky(x @ W1 + b1) ----------------------
// 128x128 tile, BK=16, 256 threads, 8x8 per thread. k-major LDS, stride 132
// (write/read patterns <=2-way bank aliasing = free). fp32 is within the
// empirically-validated psi margin (round 11: fp64 deviated 1.2e-4 from the
// np-fp32 golden and perms still matched).
__global__ __launch_bounds__(256) void gemm1_f32(
    const float* __restrict__ X,     // chunk base [rows][1024] fp32
    const float* __restrict__ W1,    // [1024][4096] fp32
    const float* __restrict__ b1,    // [4096] fp32
    float* __restrict__ Hout) {      // chunk base [rows][4096] fp32
  __shared__ float As[16][132];   // [k][m]
  __shared__ float Bs[16][132];   // [k][n]
  int t = threadIdx.x;
  int nt = blockIdx.x & 31;      // 4096/128 n-tiles; fastest -> x-panel L2 reuse
  int mt = blockIdx.x >> 5;
  int m0 = mt * 128, n0 = nt * 128;
  int tm = t & 15, tn = t >> 4;

  float acc[8][8];
#pragma unroll
  for (int r = 0; r < 8; ++r)
#pragma unroll
    for (int c = 0; c < 8; ++c) acc[r][c] = 0.0f;

  for (int k0 = 0; k0 < FDIM; k0 += 16) {
    __syncthreads();
#pragma unroll
    for (int e = 0; e < 2; ++e) {
      int idx = t + 256 * e;
      // A-tile: 128 m x 16 k (x row-major) -> scatter to k-major As
      int ma = idx >> 2, sa = idx & 3;
      float4 va = *(const float4*)(X + (size_t)(m0 + ma) * FDIM + k0 + sa * 4);
      As[sa * 4 + 0][ma] = va.x;
      As[sa * 4 + 1][ma] = va.y;
      As[sa * 4 + 2][ma] = va.z;
      As[sa * 4 + 3][ma] = va.w;
      // B-tile: 16 k x 128 n (W1 already k-major) -> contiguous float4
      int kb = idx >> 5, cb = idx & 31;
      float4 vb = *(const float4*)(W1 + (size_t)(k0 + kb) * HDIM + n0 + cb * 4);
      *(float4*)&Bs[kb][cb * 4] = vb;
    }
    __syncthreads();
#pragma unroll
    for (int kk = 0; kk < 16; ++kk) {
      float a[8], b[8];
      *(float4*)&a[0] = *(const float4*)&As[kk][tm * 8];
      *(float4*)&a[4] = *(const float4*)&As[kk][tm * 8 + 4];
      *(float4*)&b[0] = *(const float4*)&Bs[kk][tn * 8];
      *(float4*)&b[4] = *(const float4*)&Bs[kk][tn * 8 + 4];
#pragma unroll
      for (int r = 0; r < 8; ++r)
#pragma unroll
        for (int c = 0; c < 8; ++c) acc[r][c] = fmaf(a[r], b[c], acc[r][c]);
    }
  }

  int gm = m0 + tm * 8, gn = n0 + tn * 8;
  float bias[8];
#pragma unroll
  for (int c = 0; c < 8; ++c) bias[c] = b1[gn + c];
#pragma unroll
  for (int r = 0; r < 8; ++r) {
    float o[8];
#pragma unroll
    for (int c = 0; c < 8; ++c) {
      float v = acc[r][c] + bias[c];
      o[c] = v >= 0.0f ? v : 0.01f * v;
    }
    *(float4*)(Hout + (size_t)(gm + r) * HDIM + gn)     = *(float4*)&o[0];
    *(float4*)(Hout + (size_t)(gm + r) * HDIM + gn + 4) = *(float4*)&o[4];
  }
}

// ---------------- GEMM2: M = h @ W2 (fp64 accumulate from fp32 h) -----------
__global__ __launch_bounds__(256) void gemm2_kernel(
    const float* __restrict__ hchunk,        // chunk base [rows][4096] fp32
    const float* __restrict__ W2,            // [4096][50] fp32
    double* __restrict__ M64,                // [6400][50]
    int row0) {
  __shared__ __align__(16) float hs[32 * 64];
  __shared__ float w2s[64 * 52];
  int t = threadIdx.x;
  int c = t & 63, g = t >> 6;                // g = wave id; rows g, g+4, ..., g+28
  double acc[8] = {0, 0, 0, 0, 0, 0, 0, 0};
  const float* hbase = hchunk + (size_t)blockIdx.x * 32 * HDIM;

  for (int k0 = 0; k0 < HDIM; k0 += 64) {
    __syncthreads();
    {
      int row = t >> 3, seg = (t & 7) * 8;
      const float4* src = (const float4*)(hbase + (size_t)row * HDIM + k0 + seg);
      float4 v0 = src[0], v1 = src[1];
      float4* dst = (float4*)(hs + row * 64 + seg);
      dst[0] = v0; dst[1] = v1;
    }
    for (int idx = t; idx < 3200; idx += 256) {     // 64 k x 50 c, coalesced
      int cc = idx % 50, kk = idx / 50;
      w2s[kk * 52 + cc] = W2[(size_t)k0 * NMAT + idx];
    }
    __syncthreads();
    if (c < NMAT) {
#pragma unroll 4
      for (int kk = 0; kk < 64; kk += 2) {
        double w0 = (double)w2s[kk * 52 + c];
        double w1 = (double)w2s[kk * 52 + 52 + c];
#pragma unroll
        for (int i = 0; i < 8; ++i) {
          float2 hv = *(const float2*)&hs[(g + i * 4) * 64 + kk];   // broadcast
          acc[i] = fma((double)hv.x, w0, acc[i]);
          acc[i] = fma((double)hv.y, w1, acc[i]);
        }
      }
    }
  }
  if (c < NMAT) {
#pragma unroll
    for (int i = 0; i < 8; ++i)
      M64[(size_t)(row0 + blockIdx.x * 32 + g + i * 4) * NMAT + c] = acc[i];
  }
}

// ---------------- Sinkhorn (fp64): P=exp(leaky(M+b2)); 5x row/col norm ------
__global__ __launch_bounds__(64) void sinkhorn_kernel(
    double* __restrict__ M64, const float* __restrict__ b2,
    float* __restrict__ out_psi, float* __restrict__ out_X) {
  int b = blockIdx.x, lane = threadIdx.x;
  __shared__ double P[2500];
  __shared__ double rs[50];
  const size_t base = (size_t)b * 2500;
  for (int e = lane; e < 2500; e += 64) {
    double m = M64[base + e] + (double)b2[e % 50];
    m = m >= 0.0 ? m : 0.01 * m;      // leaky_relu in fp64
    P[e] = exp(m);                    // TAU = 1.0
  }
  __syncthreads();
  for (int it = 0; it < 5; ++it) {
    if (lane < 50) { double s = 0; for (int j = 0; j < 50; ++j) s += P[lane * 50 + j]; rs[lane] = s; }
    __syncthreads();
    for (int e = lane; e < 2500; e += 64) P[e] /= rs[e / 50];   // axis=2
    __syncthreads();
    if (lane < 50) { double s = 0; for (int r = 0; r < 50; ++r) s += P[r * 50 + lane]; rs[lane] = s; }
    __syncthreads();
    for (int e = lane; e < 2500; e += 64) P[e] /= rs[e % 50];   // axis=1
    __syncthreads();
  }
  for (int e = lane; e < 2500; e += 64) {
    double pv = P[e];
    M64[base + e] = pv;               // psi64 in-place
    float f = (float)pv;
    out_psi[base + e] = f;
    out_X[base + e] = f;              // ALPHA=1.0 => X == psi exactly
  }
}

// ---------------- Hungarian (exact replica of the reference's algorithm, ----
// including its dead-minv behavior), fp64, one wave per batch. FP32 outputs.
__global__ __launch_bounds__(64) void hungarian_kernel(
    const double* __restrict__ psi64, float* __restrict__ out_perms,
    float* __restrict__ out_dist) {
  int b = blockIdx.x, lane = threadIdx.x;
  __shared__ double cost[2500];
  __shared__ double u[51];
  __shared__ int p[51];
  __shared__ int wayl[51];
  const double* P = psi64 + (size_t)b * 2500;
  for (int e = lane; e < 2500; e += 64) cost[e] = -P[e];
  if (lane < 51) { u[lane] = 0.0; p[lane] = 0; }
  __syncthreads();
  double v = 0.0;                      // v[lane+1]
  bool lactive = lane < NMAT;

  for (int i = 1; i <= NMAT; ++i) {
    bool used = false;
    int way = 0;
    int j0 = 0, j1 = 0;
    for (int guard = 0; guard < 64; ++guard) {   // defensive cap (normally <=51)
      if (lane == j0 - 1) used = true;           // used[j0] = True (j0>=1)
      int i0 = (j0 == 0) ? i : p[j0];
      double ui0 = u[i0];
      double cand = HINF;
      if (lactive && !used) {
        cand = cost[(i0 - 1) * NMAT + lane] - ui0 - v;
        way = j0;                                // way set for ALL free cols (dead-minv)
      }
      double m = cand;
#pragma unroll
      for (int s = 32; s > 0; s >>= 1) {
        double o = __shfl_xor(m, s, 64);
        m = (o < m) ? o : m;
      }
      unsigned long long bal = __ballot(cand == m);
      j1 = (int)__builtin_ctzll(bal) + 1;        // np.argmin tie-break: lowest j
      double delta = m;
      __syncthreads();
      if (used) { v -= delta; u[p[lane + 1]] += delta; }   // distinct rows, no race
      if (lane == 63) u[i] += delta;                       // j=0 column: p[0]=i
      __syncthreads();
      j0 = j1;
      if (p[j0] == 0) break;
    }
    if (lactive) wayl[lane + 1] = way;
    __syncthreads();
    if (lane == 0) {                   // augment (serial, path <= 50)
      int j = j1;
      while (j != 0) {
        int jw = wayl[j];
        p[j] = (jw == 0) ? i : p[jw];
        j = jw;
      }
    }
    __syncthreads();
  }

  // perms one-hot + dist (fp32 outputs)
  size_t pbase = (size_t)b * 2500;
  for (int e = lane; e < 2500; e += 64) out_perms[pbase + e] = 0.0f;
  __syncthreads();
  double val = 0.0;
  if (lactive) {
    int row = p[lane + 1] - 1;
    if (row < 0) row = 0;              // defensive clamp (provably unreachable)
    if (row > 49) row = 49;
    out_perms[pbase + (size_t)row * NMAT + lane] = 1.0f;
    val = P[(size_t)row * NMAT + lane];
  }
#pragma unroll
  for (int s = 32; s > 0; s >>= 1) val += __shfl_xor(val, s, 64);
  if (lane == 0) out_dist[b] = (float)(val / (double)NMAT);
}

// ---------------------------------------------------------------------------
extern "C" void kernel_launch(void* const* d_in, const int* in_sizes, int n_in,
                              void* d_out, int out_size, void* d_ws, size_t ws_size,
                              hipStream_t stream) {
  const float* x  = (const float*)d_in[0];   // fp32 per the reference dtypes
  const float* W1 = (const float*)d_in[1];
  const float* b1 = (const float*)d_in[2];
  const float* W2 = (const float*)d_in[3];
  const float* b2 = (const float*)d_in[4];
  float* out = (float*)d_out;                // outputs float32 (round-8/11 finding)
  float* out_psi   = out;
  float* out_perms = out + PSIZE;
  float* out_X     = out + 2 * PSIZE;
  float* out_dist  = out + 3 * PSIZE;

  if (ws_size < (size_t)WS_MIN) return;

  char* ws = (char*)d_ws;
  double* M64 = (double*)(ws + WS_M_OFF);
  float* hbuf = (float*)(ws + WS_H_OFF);
  long long avail = (long long)ws_size - WS_H_OFF;
  int max_rows = (int)(avail / (HDIM * 4));
  max_rows = (max_rows / 128) * 128;
  if (max_rows > ROWS) max_rows = ROWS;

  for (int r0 = 0; r0 < ROWS; r0 += max_rows) {
    int rows = (ROWS - r0 < max_rows) ? (ROWS - r0) : max_rows;
    hipLaunchKernelGGL(gemm1_f32, dim3((rows / 128) * 32), dim3(256), 0, stream,
                       x + (size_t)r0 * FDIM, W1, b1, hbuf);
    hipLaunchKernelGGL(gemm2_kernel, dim3(rows / 32), dim3(256), 0, stream,
                       hbuf, W2, M64, r0);
  }
  hipLaunchKernelGGL(sinkhorn_kernel, dim3(BATCH), dim3(64), 0, stream,
                     M64, b2, out_psi, out_X);
  hipLaunchKernelGGL(hungarian_kernel, dim3(BATCH), dim3(64), 0, stream,
                     M64, out_perms, out_dist);
}

// Round 14
// 715.531 us; speedup vs baseline: 3.0894x; 1.9663x over previous
//
#include <hip/hip_runtime.h>

// Problem constants
#define NMAT 50
#define BATCH 128
#define FDIM 1024
#define HDIM 4096
#define ROWS 6400            // BATCH*NMAT
#define PSIZE 320000         // BATCH*NMAT*NMAT
#define HINF 1e18

// ws layout (bytes):
//   Mpart: [0, 10240000)      fp64 [4][6400][50] split-K partials;
//                             partial 0 is overwritten with psi64 by sinkhorn
//   hbuf : [10240000, ...)    fp32 [max_rows][4096]
#define WS_M_OFF   0
#define WS_H_OFF   10240000LL
#define WS_MIN     (WS_H_OFF + 128LL * HDIM * 4)   // ~12.3 MB

typedef __bf16 bf16x8 __attribute__((ext_vector_type(8)));
typedef float f32x4 __attribute__((ext_vector_type(4)));

__device__ __forceinline__ float bf16_to_f32(unsigned short h) {
  return __uint_as_float(((unsigned int)h) << 16);
}
__device__ __forceinline__ unsigned short f32_to_bf16(float f) {
  unsigned int u = __float_as_uint(f);
  u += 0x7FFFu + ((u >> 16) & 1u);   // RNE
  return (unsigned short)(u >> 16);
}

// ---------------- GEMM1 (split-bf16 MFMA): h = leaky(x @ W1 + b1) -----------
// x = x_hi + x_lo (bf16 pair), W1 likewise; h = hi*hi + hi*lo + lo*hi (fp32
// MFMA accumulate). Error ~2^-17 relative — same class as fp32 reordering,
// inside the round-11/13-validated psi margin. 128x128 tile, BK=32, 4 waves.
// LDS layout [kgroup][row][8]: staging writes and fragment reads are
// lane-contiguous (conflict-free). C/D mapping per m89: col=lane&15,
// row=(lane>>4)*4+reg.
__global__ __launch_bounds__(256) void gemm1_mfma(
    const float* __restrict__ X,     // chunk base [rows][1024] fp32
    const float* __restrict__ W1,    // [1024][4096] fp32
    const float* __restrict__ b1,    // [4096] fp32
    float* __restrict__ Hout) {      // chunk base [rows][4096] fp32
  __shared__ __align__(16) unsigned short Ah[4 * 128 * 8];
  __shared__ __align__(16) unsigned short Al[4 * 128 * 8];
  __shared__ __align__(16) unsigned short Bh[4 * 128 * 8];
  __shared__ __align__(16) unsigned short Bl[4 * 128 * 8];
  int t = threadIdx.x;
  int wave = t >> 6, lane = t & 63;
  int nt = blockIdx.x & 31;      // 4096/128 n-tiles
  int mt = blockIdx.x >> 5;
  int m0 = mt * 128, n0 = nt * 128;
  int wm = wave >> 1, wn = wave & 1;
  int fr = lane & 15, fg = lane >> 4;

  f32x4 acc[4][4];
#pragma unroll
  for (int i = 0; i < 4; ++i)
#pragma unroll
    for (int j = 0; j < 4; ++j) acc[i][j] = (f32x4){0.f, 0.f, 0.f, 0.f};

  for (int k0 = 0; k0 < FDIM; k0 += 32) {
    __syncthreads();               // previous-iter fragment reads done
    // ---- stage A (x rows -> k-group of this wave) ----
#pragma unroll
    for (int half = 0; half < 2; ++half) {
      int m = lane + half * 64;
      const float* src = X + (size_t)(m0 + m) * FDIM + k0 + wave * 8;
      float4 v0 = *(const float4*)src;
      float4 v1 = *(const float4*)(src + 4);
      float f0 = v0.x, f1 = v0.y, f2 = v0.z, f3 = v0.w;
      float f4 = v1.x, f5 = v1.y, f6 = v1.z, f7 = v1.w;
      unsigned short h0 = f32_to_bf16(f0), h1 = f32_to_bf16(f1),
                     h2 = f32_to_bf16(f2), h3 = f32_to_bf16(f3),
                     h4 = f32_to_bf16(f4), h5 = f32_to_bf16(f5),
                     h6 = f32_to_bf16(f6), h7 = f32_to_bf16(f7);
      unsigned short l0 = f32_to_bf16(f0 - bf16_to_f32(h0)),
                     l1 = f32_to_bf16(f1 - bf16_to_f32(h1)),
                     l2 = f32_to_bf16(f2 - bf16_to_f32(h2)),
                     l3 = f32_to_bf16(f3 - bf16_to_f32(h3)),
                     l4 = f32_to_bf16(f4 - bf16_to_f32(h4)),
                     l5 = f32_to_bf16(f5 - bf16_to_f32(h5)),
                     l6 = f32_to_bf16(f6 - bf16_to_f32(h6)),
                     l7 = f32_to_bf16(f7 - bf16_to_f32(h7));
      int base = (wave * 128 + m) * 8;
      uint4 hv, lv;
      hv.x = h0 | ((unsigned)h1 << 16); hv.y = h2 | ((unsigned)h3 << 16);
      hv.z = h4 | ((unsigned)h5 << 16); hv.w = h6 | ((unsigned)h7 << 16);
      lv.x = l0 | ((unsigned)l1 << 16); lv.y = l2 | ((unsigned)l3 << 16);
      lv.z = l4 | ((unsigned)l5 << 16); lv.w = l6 | ((unsigned)l7 << 16);
      *(uint4*)&Ah[base] = hv;
      *(uint4*)&Al[base] = lv;
    }
    // ---- stage B (W1 transposed gather: 8 coalesced row-reads per half) ----
#pragma unroll
    for (int half = 0; half < 2; ++half) {
      int n = lane + half * 64;
      float f[8];
#pragma unroll
      for (int j = 0; j < 8; ++j)
        f[j] = W1[(size_t)(k0 + wave * 8 + j) * HDIM + n0 + n];
      unsigned short h[8], l[8];
#pragma unroll
      for (int j = 0; j < 8; ++j) {
        h[j] = f32_to_bf16(f[j]);
        l[j] = f32_to_bf16(f[j] - bf16_to_f32(h[j]));
      }
      int base = (wave * 128 + n) * 8;
      uint4 hv, lv;
      hv.x = h[0] | ((unsigned)h[1] << 16); hv.y = h[2] | ((unsigned)h[3] << 16);
      hv.z = h[4] | ((unsigned)h[5] << 16); hv.w = h[6] | ((unsigned)h[7] << 16);
      lv.x = l[0] | ((unsigned)l[1] << 16); lv.y = l[2] | ((unsigned)l[3] << 16);
      lv.z = l[4] | ((unsigned)l[5] << 16); lv.w = l[6] | ((unsigned)l[7] << 16);
      *(uint4*)&Bh[base] = hv;
      *(uint4*)&Bl[base] = lv;
    }
    __syncthreads();
    // ---- fragments + MFMA ----
    bf16x8 ah[4], al[4], bh[4], bl[4];
#pragma unroll
    for (int i = 0; i < 4; ++i) {
      int arow = (fg * 128 + wm * 64 + i * 16 + fr) * 8;
      ah[i] = *(const bf16x8*)&Ah[arow];
      al[i] = *(const bf16x8*)&Al[arow];
      int brow = (fg * 128 + wn * 64 + i * 16 + fr) * 8;
      bh[i] = *(const bf16x8*)&Bh[brow];
      bl[i] = *(const bf16x8*)&Bl[brow];
    }
#pragma unroll
    for (int i = 0; i < 4; ++i)
#pragma unroll
      for (int j = 0; j < 4; ++j) {
        acc[i][j] = __builtin_amdgcn_mfma_f32_16x16x32_bf16(ah[i], bh[j], acc[i][j], 0, 0, 0);
        acc[i][j] = __builtin_amdgcn_mfma_f32_16x16x32_bf16(ah[i], bl[j], acc[i][j], 0, 0, 0);
        acc[i][j] = __builtin_amdgcn_mfma_f32_16x16x32_bf16(al[i], bh[j], acc[i][j], 0, 0, 0);
      }
  }

  // Epilogue: col=lane&15, row=(lane>>4)*4+reg [m89-verified]
  int colb = n0 + wn * 64 + fr;
  int rowb = m0 + wm * 64 + fg * 4;
#pragma unroll
  for (int j = 0; j < 4; ++j) {
    float bias = b1[colb + j * 16];
#pragma unroll
    for (int i = 0; i < 4; ++i)
#pragma unroll
      for (int r = 0; r < 4; ++r) {
        float v = acc[i][j][r] + bias;
        v = v >= 0.0f ? v : 0.01f * v;
        Hout[(size_t)(rowb + i * 16 + r) * HDIM + colb + j * 16] = v;
      }
  }
}

// ---------------- GEMM2: Mpart[kz] = h @ W2 (fp64, split-K=4) ---------------
__global__ __launch_bounds__(256) void gemm2_kernel(
    const float* __restrict__ hchunk,        // chunk base [rows][4096] fp32
    const float* __restrict__ W2,            // [4096][50] fp32
    double* __restrict__ Mpart,              // [4][6400][50]
    int row0) {
  __shared__ __align__(16) float hs[32 * 64];
  __shared__ float w2s[64 * 52];
  int t = threadIdx.x;
  int c = t & 63, g = t >> 6;                // rows g, g+4, ..., g+28
  int kz = blockIdx.y;
  double acc[8] = {0, 0, 0, 0, 0, 0, 0, 0};
  const float* hbase = hchunk + (size_t)blockIdx.x * 32 * HDIM;

  for (int k0 = kz * 1024; k0 < kz * 1024 + 1024; k0 += 64) {
    __syncthreads();
    {
      int row = t >> 3, seg = (t & 7) * 8;
      const float4* src = (const float4*)(hbase + (size_t)row * HDIM + k0 + seg);
      float4 v0 = src[0], v1 = src[1];
      float4* dst = (float4*)(hs + row * 64 + seg);
      dst[0] = v0; dst[1] = v1;
    }
    for (int idx = t; idx < 3200; idx += 256) {     // 64 k x 50 c, coalesced
      int cc = idx % 50, kk = idx / 50;
      w2s[kk * 52 + cc] = W2[(size_t)k0 * NMAT + idx];
    }
    __syncthreads();
    if (c < NMAT) {
#pragma unroll 4
      for (int kk = 0; kk < 64; kk += 2) {
        double w0 = (double)w2s[kk * 52 + c];
        double w1 = (double)w2s[kk * 52 + 52 + c];
#pragma unroll
        for (int i = 0; i < 8; ++i) {
          float2 hv = *(const float2*)&hs[(g + i * 4) * 64 + kk];   // broadcast
          acc[i] = fma((double)hv.x, w0, acc[i]);
          acc[i] = fma((double)hv.y, w1, acc[i]);
        }
      }
    }
  }
  if (c < NMAT) {
    double* Mout = Mpart + (size_t)kz * PSIZE;
#pragma unroll
    for (int i = 0; i < 8; ++i)
      Mout[(size_t)(row0 + blockIdx.x * 32 + g + i * 4) * NMAT + c] = acc[i];
  }
}

// ---------------- Sinkhorn (fp64): merge 4 partials, P=exp(leaky(M+b2)), ----
// 5x row/col norm. Writes psi64 into Mpart[0] region (block-local, safe).
__global__ __launch_bounds__(64) void sinkhorn_kernel(
    double* __restrict__ Mpart, const float* __restrict__ b2,
    float* __restrict__ out_psi, float* __restrict__ out_X) {
  int b = blockIdx.x, lane = threadIdx.x;
  __shared__ double P[2500];
  __shared__ double rs[50];
  const size_t base = (size_t)b * 2500;
  for (int e = lane; e < 2500; e += 64) {
    double m = Mpart[base + e] + Mpart[PSIZE + base + e] +
               Mpart[2 * PSIZE + base + e] + Mpart[3 * PSIZE + base + e];
    m += (double)b2[e % 50];
    m = m >= 0.0 ? m : 0.01 * m;      // leaky_relu in fp64
    P[e] = exp(m);                    // TAU = 1.0
  }
  __syncthreads();
  for (int it = 0; it < 5; ++it) {
    if (lane < 50) { double s = 0; for (int j = 0; j < 50; ++j) s += P[lane * 50 + j]; rs[lane] = s; }
    __syncthreads();
    for (int e = lane; e < 2500; e += 64) P[e] /= rs[e / 50];   // axis=2
    __syncthreads();
    if (lane < 50) { double s = 0; for (int r = 0; r < 50; ++r) s += P[r * 50 + lane]; rs[lane] = s; }
    __syncthreads();
    for (int e = lane; e < 2500; e += 64) P[e] /= rs[e % 50];   // axis=1
    __syncthreads();
  }
  for (int e = lane; e < 2500; e += 64) {
    double pv = P[e];
    Mpart[base + e] = pv;             // psi64 in-place (partial-0 region)
    float f = (float)pv;
    out_psi[base + e] = f;
    out_X[base + e] = f;              // ALPHA=1.0 => X == psi exactly
  }
}

// ---------------- Hungarian (exact replica of the reference's algorithm, ----
// including its dead-minv behavior), fp64, one wave per batch. FP32 outputs.
__global__ __launch_bounds__(64) void hungarian_kernel(
    const double* __restrict__ psi64, float* __restrict__ out_perms,
    float* __restrict__ out_dist) {
  int b = blockIdx.x, lane = threadIdx.x;
  __shared__ double cost[2500];
  __shared__ double u[51];
  __shared__ int p[51];
  __shared__ int wayl[51];
  const double* P = psi64 + (size_t)b * 2500;
  for (int e = lane; e < 2500; e += 64) cost[e] = -P[e];
  if (lane < 51) { u[lane] = 0.0; p[lane] = 0; }
  __syncthreads();
  double v = 0.0;                      // v[lane+1]
  bool lactive = lane < NMAT;

  for (int i = 1; i <= NMAT; ++i) {
    bool used = false;
    int way = 0;
    int j0 = 0, j1 = 0;
    for (int guard = 0; guard < 64; ++guard) {   // defensive cap (normally <=51)
      if (lane == j0 - 1) used = true;           // used[j0] = True (j0>=1)
      int i0 = (j0 == 0) ? i : p[j0];
      double ui0 = u[i0];
      double cand = HINF;
      if (lactive && !used) {
        cand = cost[(i0 - 1) * NMAT + lane] - ui0 - v;
        way = j0;                                // way set for ALL free cols (dead-minv)
      }
      double m = cand;
#pragma unroll
      for (int s = 32; s > 0; s >>= 1) {
        double o = __shfl_xor(m, s, 64);
        m = (o < m) ? o : m;
      }
      unsigned long long bal = __ballot(cand == m);
      j1 = (int)__builtin_ctzll(bal) + 1;        // np.argmin tie-break: lowest j
      double delta = m;
      __syncthreads();
      if (used) { v -= delta; u[p[lane + 1]] += delta; }   // distinct rows, no race
      if (lane == 63) u[i] += delta;                       // j=0 column: p[0]=i
      __syncthreads();
      j0 = j1;
      if (p[j0] == 0) break;
    }
    if (lactive) wayl[lane + 1] = way;
    __syncthreads();
    if (lane == 0) {                   // augment (serial, path <= 50)
      int j = j1;
      while (j != 0) {
        int jw = wayl[j];
        p[j] = (jw == 0) ? i : p[jw];
        j = jw;
      }
    }
    __syncthreads();
  }

  // perms one-hot + dist (fp32 outputs)
  size_t pbase = (size_t)b * 2500;
  for (int e = lane; e < 2500; e += 64) out_perms[pbase + e] = 0.0f;
  __syncthreads();
  double val = 0.0;
  if (lactive) {
    int row = p[lane + 1] - 1;
    if (row < 0) row = 0;              // defensive clamp (provably unreachable)
    if (row > 49) row = 49;
    out_perms[pbase + (size_t)row * NMAT + lane] = 1.0f;
    val = P[(size_t)row * NMAT + lane];
  }
#pragma unroll
  for (int s = 32; s > 0; s >>= 1) val += __shfl_xor(val, s, 64);
  if (lane == 0) out_dist[b] = (float)(val / (double)NMAT);
}

// ---------------------------------------------------------------------------
extern "C" void kernel_launch(void* const* d_in, const int* in_sizes, int n_in,
                              void* d_out, int out_size, void* d_ws, size_t ws_size,
                              hipStream_t stream) {
  const float* x  = (const float*)d_in[0];   // fp32 per the reference dtypes
  const float* W1 = (const float*)d_in[1];
  const float* b1 = (const float*)d_in[2];
  const float* W2 = (const float*)d_in[3];
  const float* b2 = (const float*)d_in[4];
  float* out = (float*)d_out;                // outputs float32 (round-8/11 finding)
  float* out_psi   = out;
  float* out_perms = out + PSIZE;
  float* out_X     = out + 2 * PSIZE;
  float* out_dist  = out + 3 * PSIZE;

  if (ws_size < (size_t)WS_MIN) return;

  char* ws = (char*)d_ws;
  double* Mpart = (double*)(ws + WS_M_OFF);
  float* hbuf = (float*)(ws + WS_H_OFF);
  long long avail = (long long)ws_size - WS_H_OFF;
  int max_rows = (int)(avail / (HDIM * 4));
  max_rows = (max_rows / 128) * 128;
  if (max_rows > ROWS) max_rows = ROWS;

  for (int r0 = 0; r0 < ROWS; r0 += max_rows) {
    int rows = (ROWS - r0 < max_rows) ? (ROWS - r0) : max_rows;
    hipLaunchKernelGGL(gemm1_mfma, dim3((rows / 128) * 32), dim3(256), 0, stream,
                       x + (size_t)r0 * FDIM, W1, b1, hbuf);
    hipLaunchKernelGGL(gemm2_kernel, dim3(rows / 32, 4), dim3(256), 0, stream,
                       hbuf, W2, Mpart, r0);
  }
  hipLaunchKernelGGL(sinkhorn_kernel, dim3(BATCH), dim3(64), 0, stream,
                     Mpart, b2, out_psi, out_X);
  hipLaunchKernelGGL(hungarian_kernel, dim3(BATCH), dim3(64), 0, stream,
                     Mpart, out_perms, out_dist);
}